// Round 14
// baseline (84.168 us; speedup 1.0000x reference)
//
#include <hip/hip_runtime.h>

#define BATCH 8
#define NROW  2048
#define NF    64
#define JSPLIT 2
#define JPB   (NROW / JSPLIT)               // 1024 k per block (split path)
#define CHUNK 32
#define TOT   ((size_t)BATCH * NROW * NF)   // 1048576

typedef float  f32x4  __attribute__((ext_vector_type(4)));
typedef __bf16 bf16x8 __attribute__((ext_vector_type(8)));
typedef unsigned short u16x8 __attribute__((ext_vector_type(8)));

union frag_cast { u16x8 u; bf16x8 b; };
union hbits { __bf16 h; unsigned short u; };

#define AS1 __attribute__((address_space(1)))
#define AS3 __attribute__((address_space(3)))

__device__ __forceinline__ void gld16u(const unsigned short* g, unsigned short* l) {
  __builtin_amdgcn_global_load_lds((const AS1 void*)g, (AS3 void*)l, 16, 0, 0);
}

// ---- pass 1: transpose x, split into 3 bf16 levels (RNE, exact residuals) ----
__global__ __launch_bounds__(256, 4)
void prep_x(const float* __restrict__ xg, unsigned short* __restrict__ xs) {
  __shared__ float t[64][65];
  const int b  = blockIdx.y;
  const int j0 = blockIdx.x * 64;
  const int l  = threadIdx.x & 63;
  const int g  = threadIdx.x >> 6;
  const float* src = xg + ((size_t)b * NROW + j0) * NF;
#pragma unroll
  for (int k = 0; k < 16; ++k) {
    const int j = g * 16 + k;
    t[j][l] = src[(size_t)j * NF + l];
  }
  __syncthreads();
#pragma unroll
  for (int k = 0; k < 16; ++k) {
    const int f = g * 16 + k;
    const float v = t[l][f];
    hbits b0, b1, b2;
    b0.h = (__bf16)v;
    const float r  = v - (float)b0.h;     // exact
    b1.h = (__bf16)r;
    const float r2 = r - (float)b1.h;     // exact
    b2.h = (__bf16)r2;
    const size_t o = ((size_t)b * NF + f) * NROW + j0 + l;
    xs[o]           = b0.u;
    xs[o + TOT]     = b1.u;
    xs[o + 2 * TOT] = b2.u;
  }
}

// split 8 f32 -> 3 bf16 fragments via native RNE casts (compiler -> cvt_pk)
__device__ __forceinline__ void split8(const f32x4 q0, const f32x4 q1,
                                       frag_cast* Af) {
  float av[8];
  *(f32x4*)&av[0] = q0;
  *(f32x4*)&av[4] = q1;
  bf16x8 h0, h1, h2;
#pragma unroll
  for (int e = 0; e < 8; ++e) {
    const __bf16 b0 = (__bf16)av[e];
    const float  r  = av[e] - (float)b0;   // exact
    const __bf16 b1 = (__bf16)r;
    const float  r2 = r - (float)b1;       // exact
    h0[e] = b0; h1[e] = b1; h2[e] = (__bf16)r2;
  }
  Af[0].b = h0; Af[1].b = h1; Af[2].b = h2;
}

// ---- pass 2: split-bf16 MFMA GEMM, wave = 16r x 32c ----
// Block 32r x 64c (4 waves: rowq = wv&1, colh = wv>>1), grid 1024 =
// JSPLIT2 x 8 batch x 64 row-tiles, 4 blocks/CU. Per wave-chunk: 1 split8,
// 6 ds_read_b128 (2 nt x 3 lvl, immediate offsets), 12 MFMA (2 chains).
// B: LDS dbuf 2x12KB via gld_lds pre-swizzled source; A: global->reg,
// prefetch-1 (coalesced 16-line wave reads). b = flat&7 == XCD.
template <bool DIRECT>
__global__ __launch_bounds__(256, 4)
void gemm_mfma(const float* __restrict__ ag, const unsigned short* __restrict__ xs,
               float* __restrict__ outg, float* __restrict__ wp) {
  __shared__ __align__(16) unsigned short sB[2][3 * 64 * CHUNK];   // 2 x 12KB

  const int tid  = threadIdx.x;
  const int ln   = tid & 63;
  const int wv   = tid >> 6;
  const int ln15 = ln & 15;          // A row / B col / D col (in 16-tile)
  const int g    = ln >> 4;          // k-octet / D row-group
  const int rowq = wv & 1;           // wave row group (16 rows)
  const int colh = wv >> 1;          // wave col half (32 cols)
  const int bkey = (ln15 >> 1) & 3;

  const int flat = blockIdx.x;
  const int b    = flat & 7;                      // batch == XCD
  const int rr   = flat >> 3;
  const int bx   = rr & 63;
  const int z    = DIRECT ? 0 : (rr >> 6);
  const int i0   = bx * 32;
  const int jb   = z * (DIRECT ? 0 : JPB);
  const int nch  = (DIRECT ? NROW : JPB) / CHUNK;   // 64 or 32

  const float* aA =
      ag + ((size_t)b * NROW + i0 + rowq * 16 + ln15) * NROW + jb + g * 8;
  const unsigned short* xB = xs + (size_t)b * NF * NROW;

  // B-read base (u16 units), loop-invariant; nt/lvl are immediate offsets
  const int boff = (colh * 32 + ln15) * 32 + (g ^ bkey) * 8;
  const unsigned short* pBr[2] = { &sB[0][boff], &sB[1][boff] };

  auto stageB = [&](int buf, int j0) {
#pragma unroll
    for (int lvl = 0; lvl < 3; ++lvl) {
      const int n = tid >> 2;
      const int q = (tid & 3) ^ ((n >> 1) & 3);
      gld16u(xB + (size_t)lvl * TOT + (size_t)n * NROW + j0 + q * 8,
             &sB[buf][0] + (lvl * 256 + wv * 64) * 8);
    }
  };

  double macc[2][4];
#pragma unroll
  for (int i = 0; i < 2; ++i)
#pragma unroll
    for (int j = 0; j < 4; ++j) macc[i][j] = 0.0;

  constexpr int AI[6] = {2, 0, 1, 1, 0, 0};
  constexpr int BI[6] = {0, 2, 1, 0, 1, 0};

  stageB(0, jb);
  f32x4 A0 = *(const f32x4*)(aA);
  f32x4 A1 = *(const f32x4*)(aA + 4);

#pragma unroll 1
  for (int t = 0; t < nch; ++t) {
    __syncthreads();                  // stage(t) visible; buf^1 free
    if (t + 1 < nch) stageB((t + 1) & 1, jb + (t + 1) * CHUNK);
    const int tn = (t + 1 < nch) ? (t + 1) : t;
    f32x4 N0 = *(const f32x4*)(aA + (size_t)tn * CHUNK);
    f32x4 N1 = *(const f32x4*)(aA + (size_t)tn * CHUNK + 4);

    frag_cast Af[3];
    split8(A0, A1, Af);
    A0 = N0; A1 = N1;

    const unsigned short* pB = pBr[t & 1];
    frag_cast Bv[2][3];
#pragma unroll
    for (int nt = 0; nt < 2; ++nt)
#pragma unroll
      for (int lvl = 0; lvl < 3; ++lvl)
        Bv[nt][lvl].u = *(const u16x8*)(pB + nt * 512 + lvl * 2048);

    f32x4 c[2];
    c[0] = (f32x4){0.f, 0.f, 0.f, 0.f};
    c[1] = (f32x4){0.f, 0.f, 0.f, 0.f};
#pragma unroll
    for (int term = 0; term < 6; ++term)
#pragma unroll
      for (int nt = 0; nt < 2; ++nt)
        c[nt] = __builtin_amdgcn_mfma_f32_16x16x32_bf16(
            Af[AI[term]].b, Bv[nt][BI[term]].b, c[nt], 0, 0, 0);

#pragma unroll
    for (int nt = 0; nt < 2; ++nt) {
      macc[nt][0] += (double)c[nt].x;
      macc[nt][1] += (double)c[nt].y;
      macc[nt][2] += (double)c[nt].z;
      macc[nt][3] += (double)c[nt].w;
    }
  }

  // epilogue: D row = g*4 + r (within 16-tile), col = colh*32 + nt*16 + ln15
  if (DIRECT) {
#pragma unroll
    for (int nt = 0; nt < 2; ++nt)
#pragma unroll
      for (int r = 0; r < 4; ++r)
        outg[((size_t)b * NROW + i0 + rowq * 16 + g * 4 + r) * NF +
             colh * 32 + nt * 16 + ln15] = (macc[nt][r] > 0.5) ? 1.0f : 0.0f;
  } else {
    float* wb = wp + (size_t)z * TOT;
#pragma unroll
    for (int nt = 0; nt < 2; ++nt)
#pragma unroll
      for (int r = 0; r < 4; ++r)
        wb[((size_t)b * NROW + i0 + rowq * 16 + g * 4 + r) * NF +
           colh * 32 + nt * 16 + ln15] = (float)macc[nt][r];
  }
}

// ---- pass 3: reduce 2 partials in f64, threshold ----
__global__ __launch_bounds__(256)
void combine_thresh(const float* __restrict__ wsv, float* __restrict__ outg) {
  const size_t e = ((size_t)blockIdx.x * 256 + threadIdx.x) * 4;
  f32x4 p0 = *(const f32x4*)(wsv + e);
  f32x4 p1 = *(const f32x4*)(wsv + e + TOT);
  f32x4 o;
  o.x = (((double)p0.x + p1.x) > 0.5) ? 1.0f : 0.0f;
  o.y = (((double)p0.y + p1.y) > 0.5) ? 1.0f : 0.0f;
  o.z = (((double)p0.z + p1.z) > 0.5) ? 1.0f : 0.0f;
  o.w = (((double)p0.w + p1.w) > 0.5) ? 1.0f : 0.0f;
  *(f32x4*)(outg + e) = o;
}

extern "C" void kernel_launch(void* const* d_in, const int* in_sizes, int n_in,
                              void* d_out, int out_size, void* d_ws, size_t ws_size,
                              hipStream_t stream) {
  const float* x = (const float*)d_in[0];
  const float* a = (const float*)d_in[1];
  float* out = (float*)d_out;
  unsigned short* xs = (unsigned short*)d_ws;                 // 6 MB
  float* wp = (float*)((char*)d_ws + 3 * TOT * sizeof(unsigned short));

  prep_x<<<dim3(NROW / 64, BATCH), dim3(256), 0, stream>>>(x, xs);

  const size_t need = 3 * TOT * sizeof(unsigned short)
                    + (size_t)JSPLIT * TOT * sizeof(float);   // 14 MB
  if (ws_size >= need) {
    gemm_mfma<false><<<dim3(JSPLIT * BATCH * (NROW / 32)), dim3(256), 0, stream>>>(
        a, xs, out, wp);
    combine_thresh<<<dim3((unsigned)(TOT / 1024)), dim3(256), 0, stream>>>(wp, out);
  } else {
    gemm_mfma<true><<<dim3(BATCH * (NROW / 32)), dim3(256), 0, stream>>>(
        a, xs, out, nullptr);
  }
}

// Round 15
// 41.278 us; speedup vs baseline: 2.0391x; 2.0391x over previous
//
#include <hip/hip_runtime.h>

#define BATCH 8
#define NROW  2048
#define NF    64
#define JSPLIT 4
#define JPB   (NROW / JSPLIT)               // 512 k per block (split path)
#define CHUNK 32
#define TOT   ((size_t)BATCH * NROW * NF)   // 1048576

typedef float    f32x4 __attribute__((ext_vector_type(4)));
typedef _Float16 f16x8 __attribute__((ext_vector_type(8)));
typedef unsigned short u16x8 __attribute__((ext_vector_type(8)));

union fragh { u16x8 u; f16x8 h; };
union hbits { _Float16 h; unsigned short u; };

#define ASCALE 4096.0f     // 2^12  (a -> [0,4096): no f16 denormal pitfalls)
#define XSCALE 2048.0f     // 2^11  (|x|max ~5.5 -> ~11k < 65504)
#define THRESH 4194304.0   // 0.5 * 2^23 (product scale)

#define AS1 __attribute__((address_space(1)))
#define AS3 __attribute__((address_space(3)))

__device__ __forceinline__ void gld16u(const unsigned short* g, unsigned short* l) {
  __builtin_amdgcn_global_load_lds((const AS1 void*)g, (AS3 void*)l, 16, 0, 0);
}

// ---- pass 1: transpose x, scale by 2^11, split into 2 f16 levels ----
// v = x*2^11;  x0 = RNE_f16(v);  r = v - x0 (exact);  x1 = RNE_f16(r).
__global__ __launch_bounds__(256, 4)
void prep_x(const float* __restrict__ xg, unsigned short* __restrict__ xs) {
  __shared__ float t[64][65];
  const int b  = blockIdx.y;
  const int j0 = blockIdx.x * 64;
  const int l  = threadIdx.x & 63;
  const int g  = threadIdx.x >> 6;
  const float* src = xg + ((size_t)b * NROW + j0) * NF;
#pragma unroll
  for (int k = 0; k < 16; ++k) {
    const int j = g * 16 + k;
    t[j][l] = src[(size_t)j * NF + l];
  }
  __syncthreads();
#pragma unroll
  for (int k = 0; k < 16; ++k) {
    const int f = g * 16 + k;
    const float v = t[l][f] * XSCALE;
    hbits b0, b1;
    b0.h = (_Float16)v;
    const float r = v - (float)b0.h;      // exact (within half-ulp)
    b1.h = (_Float16)r;
    const size_t o = ((size_t)b * NF + f) * NROW + j0 + l;
    xs[o]       = b0.u;
    xs[o + TOT] = b1.u;
  }
}

// split 8 scaled f32 -> 2 f16 fragments (RNE; residual exact)
__device__ __forceinline__ void split8h(const f32x4 q0, const f32x4 q1,
                                        fragh* Af) {
  float av[8];
  *(f32x4*)&av[0] = q0;
  *(f32x4*)&av[4] = q1;
  f16x8 h0, h1;
#pragma unroll
  for (int e = 0; e < 8; ++e) {
    const float v = av[e] * ASCALE;
    const _Float16 b0 = (_Float16)v;
    const float r = v - (float)b0;        // exact
    h0[e] = b0;
    h1[e] = (_Float16)r;
  }
  Af[0].h = h0; Af[1].h = h1;
}

// ---- pass 2: 2-level f16 MFMA GEMM (r12 skeleton, 4-term product) ----
// Block: 4 waves, wave = 16 rows x 64 cols (4 n-tiles = 4 independent MFMA
// chains of 4). A: global->reg fragments (natively coalesced), prefetch-1.
// B: LDS dbuf 2 x 8KB via gld_lds, pre-swizzled source (r12's proven
// conflict-free pattern with lvl-dim = 2). b = flat&7 == XCD round-robin.
// f32 MFMA accum per 32-k chunk -> f64 masters (proven fold scheme).
template <bool DIRECT>
__global__ __launch_bounds__(256, 4)
void gemm_mfma(const float* __restrict__ ag, const unsigned short* __restrict__ xs,
               float* __restrict__ outg, float* __restrict__ wp) {
  __shared__ __align__(16) unsigned short sB[2][2 * 64 * CHUNK];   // 2 x 8KB

  const int tid  = threadIdx.x;
  const int ln   = tid & 63;
  const int wv   = tid >> 6;
  const int ln15 = ln & 15;          // A row / B col / D col (in 16-tile)
  const int g    = ln >> 4;          // k-octet / D row-group
  const int bkey = (ln15 >> 1) & 3;

  const int flat = blockIdx.x;
  const int b    = flat & 7;                      // batch == XCD
  const int rr   = flat >> 3;
  const int bx   = rr & 31;
  const int z    = DIRECT ? 0 : ((rr >> 5) & 3);
  const int i0   = bx * 64;
  const int jb   = z * JPB;
  const int nch  = (DIRECT ? NROW : JPB) / CHUNK;   // 64 or 16

  const float* aA =
      ag + ((size_t)b * NROW + i0 + wv * 16 + ln15) * NROW + jb + g * 8;
  const unsigned short* xB = xs + (size_t)b * NF * NROW;

  // stage B chunk: 2 gld_lds per thread (linear dest, inverse-swizzled src)
  auto stageB = [&](int buf, int j0) {
#pragma unroll
    for (int lvl = 0; lvl < 2; ++lvl) {
      const int n = tid >> 2;
      const int q = (tid & 3) ^ ((n >> 1) & 3);
      gld16u(xB + (size_t)lvl * TOT + (size_t)n * NROW + j0 + q * 8,
             &sB[buf][0] + (lvl * 256 + wv * 64) * 8);
    }
  };

  double macc[4][4];
#pragma unroll
  for (int i = 0; i < 4; ++i)
#pragma unroll
    for (int j = 0; j < 4; ++j) macc[i][j] = 0.0;

  // 4 terms, ascending magnitude: a1x1, a1x0, a0x1, a0x0
  constexpr int AI[4] = {1, 1, 0, 0};
  constexpr int BI[4] = {1, 0, 1, 0};

  stageB(0, jb);
  f32x4 A0 = *(const f32x4*)(aA);
  f32x4 A1 = *(const f32x4*)(aA + 4);

#pragma unroll 1
  for (int t = 0; t < nch; ++t) {
    __syncthreads();                  // stage(t) visible; buf^1 free
    if (t + 1 < nch) stageB((t + 1) & 1, jb + (t + 1) * CHUNK);
    const int tn = (t + 1 < nch) ? (t + 1) : t;
    f32x4 N0 = *(const f32x4*)(aA + (size_t)tn * CHUNK);
    f32x4 N1 = *(const f32x4*)(aA + (size_t)tn * CHUNK + 4);

    fragh Af[2];
    split8h(A0, A1, Af);
    A0 = N0; A1 = N1;

    const unsigned short* sBb = &sB[t & 1][0];
    f32x4 c[4];
#pragma unroll
    for (int nt = 0; nt < 4; ++nt) c[nt] = (f32x4){0.f, 0.f, 0.f, 0.f};

#pragma unroll
    for (int ng = 0; ng < 2; ++ng) {
      fragh Bv[2][2];
#pragma unroll
      for (int nn = 0; nn < 2; ++nn) {
        const int ncol = (ng * 2 + nn) * 16 + ln15;
        const int bq   = g ^ bkey;
#pragma unroll
        for (int lvl = 0; lvl < 2; ++lvl)
          Bv[nn][lvl].u = *(const u16x8*)(sBb + lvl * 2048 + ncol * 32 + bq * 8);
      }
#pragma unroll
      for (int term = 0; term < 4; ++term)
#pragma unroll
        for (int nn = 0; nn < 2; ++nn) {
          const int nt = ng * 2 + nn;
          c[nt] = __builtin_amdgcn_mfma_f32_16x16x32_f16(
              Af[AI[term]].h, Bv[nn][BI[term]].h, c[nt], 0, 0, 0);
        }
    }
#pragma unroll
    for (int nt = 0; nt < 4; ++nt) {
      macc[nt][0] += (double)c[nt].x;
      macc[nt][1] += (double)c[nt].y;
      macc[nt][2] += (double)c[nt].z;
      macc[nt][3] += (double)c[nt].w;
    }
  }

  // epilogue: D row = g*4 + r (within 16-tile), col = nt*16 + ln15
  if (DIRECT) {
#pragma unroll
    for (int nt = 0; nt < 4; ++nt)
#pragma unroll
      for (int r = 0; r < 4; ++r)
        outg[((size_t)b * NROW + i0 + wv * 16 + g * 4 + r) * NF + nt * 16 + ln15] =
            (macc[nt][r] > THRESH) ? 1.0f : 0.0f;
  } else {
    float* wb = wp + (size_t)z * TOT;
#pragma unroll
    for (int nt = 0; nt < 4; ++nt)
#pragma unroll
      for (int r = 0; r < 4; ++r)
        wb[((size_t)b * NROW + i0 + wv * 16 + g * 4 + r) * NF + nt * 16 + ln15] =
            (float)macc[nt][r];
  }
}

// ---- pass 3: reduce JSPLIT partials in f64, threshold (scaled) ----
__global__ __launch_bounds__(256)
void combine_thresh(const float* __restrict__ wsv, float* __restrict__ outg) {
  const size_t e = ((size_t)blockIdx.x * 256 + threadIdx.x) * 4;
  f32x4 p0 = *(const f32x4*)(wsv + e);
  f32x4 p1 = *(const f32x4*)(wsv + e + TOT);
  f32x4 p2 = *(const f32x4*)(wsv + e + 2 * TOT);
  f32x4 p3 = *(const f32x4*)(wsv + e + 3 * TOT);
  f32x4 o;
  o.x = (((double)p0.x + p1.x + p2.x + p3.x) > THRESH) ? 1.0f : 0.0f;
  o.y = (((double)p0.y + p1.y + p2.y + p3.y) > THRESH) ? 1.0f : 0.0f;
  o.z = (((double)p0.z + p1.z + p2.z + p3.z) > THRESH) ? 1.0f : 0.0f;
  o.w = (((double)p0.w + p1.w + p2.w + p3.w) > THRESH) ? 1.0f : 0.0f;
  *(f32x4*)(outg + e) = o;
}

extern "C" void kernel_launch(void* const* d_in, const int* in_sizes, int n_in,
                              void* d_out, int out_size, void* d_ws, size_t ws_size,
                              hipStream_t stream) {
  const float* x = (const float*)d_in[0];
  const float* a = (const float*)d_in[1];
  float* out = (float*)d_out;
  unsigned short* xs = (unsigned short*)d_ws;                 // 2 levels = 4 MB
  float* wp = (float*)((char*)d_ws + 2 * TOT * sizeof(unsigned short));

  prep_x<<<dim3(NROW / 64, BATCH), dim3(256), 0, stream>>>(x, xs);

  const size_t need = 2 * TOT * sizeof(unsigned short)
                    + (size_t)JSPLIT * TOT * sizeof(float);   // 20 MB
  if (ws_size >= need) {
    gemm_mfma<false><<<dim3(JSPLIT * BATCH * (NROW / 64)), dim3(256), 0, stream>>>(
        a, xs, out, wp);
    combine_thresh<<<dim3((unsigned)(TOT / 1024)), dim3(256), 0, stream>>>(wp, out);
  } else {
    gemm_mfma<true><<<dim3(BATCH * (NROW / 64)), dim3(256), 0, stream>>>(
        a, xs, out, nullptr);
  }
}

// Round 16
// 40.043 us; speedup vs baseline: 2.1019x; 1.0308x over previous
//
#include <hip/hip_runtime.h>

#define BATCH 8
#define NROW  2048
#define NF    64
#define JSPLIT 4
#define JPB   (NROW / JSPLIT)               // 512 k per block (split path)
#define CHUNK 64
#define TOT   ((size_t)BATCH * NROW * NF)   // 1048576

typedef float    f32x4 __attribute__((ext_vector_type(4)));
typedef _Float16 f16x8 __attribute__((ext_vector_type(8)));
typedef unsigned short u16x8 __attribute__((ext_vector_type(8)));

union fragh { u16x8 u; f16x8 h; };
union hbits { _Float16 h; unsigned short u; };

#define ASCALE 4096.0f     // 2^12  (a in [0,1) -> [0,4096): no f16 denormals)
#define XSCALE 2048.0f     // 2^11  (|x|max ~5.5 -> ~11k < 65504)
#define THRESH 4194304.0   // 0.5 * 2^23 (product scale)

#define AS1 __attribute__((address_space(1)))
#define AS3 __attribute__((address_space(3)))

__device__ __forceinline__ void gld16u(const unsigned short* g, unsigned short* l) {
  __builtin_amdgcn_global_load_lds((const AS1 void*)g, (AS3 void*)l, 16, 0, 0);
}

// ---- pass 1: transpose x, scale by 2^11, split into 2 f16 levels ----
__global__ __launch_bounds__(256, 4)
void prep_x(const float* __restrict__ xg, unsigned short* __restrict__ xs) {
  __shared__ float t[64][65];
  const int b  = blockIdx.y;
  const int j0 = blockIdx.x * 64;
  const int l  = threadIdx.x & 63;
  const int g  = threadIdx.x >> 6;
  const float* src = xg + ((size_t)b * NROW + j0) * NF;
#pragma unroll
  for (int k = 0; k < 16; ++k) {
    const int j = g * 16 + k;
    t[j][l] = src[(size_t)j * NF + l];
  }
  __syncthreads();
#pragma unroll
  for (int k = 0; k < 16; ++k) {
    const int f = g * 16 + k;
    const float v = t[l][f] * XSCALE;
    hbits b0, b1;
    b0.h = (_Float16)v;
    const float r = v - (float)b0.h;      // exact
    b1.h = (_Float16)r;
    const size_t o = ((size_t)b * NF + f) * NROW + j0 + l;
    xs[o]       = b0.u;
    xs[o + TOT] = b1.u;
  }
}

// split 8 scaled f32 -> 2 f16 fragments (RNE; residual exact)
__device__ __forceinline__ void split8h(const f32x4 q0, const f32x4 q1,
                                        fragh* Af) {
  float av[8];
  *(f32x4*)&av[0] = q0;
  *(f32x4*)&av[4] = q1;
  f16x8 h0, h1;
#pragma unroll
  for (int e = 0; e < 8; ++e) {
    const float v = av[e] * ASCALE;
    const _Float16 b0 = (_Float16)v;
    const float r = v - (float)b0;        // exact
    h0[e] = b0;
    h1[e] = (_Float16)r;
  }
  Af[0].h = h0; Af[1].h = h1;
}

// ---- pass 2: 2-level f16 MFMA GEMM, CHUNK=64 (r15 structure, amortized) ----
// Block: 4 waves, wave = 16 rows x 64 cols (4 n-tiles). Per chunk (64 k):
// 2 subs x {1 split8h, 8 ds_read_b128, 16 MFMA}, ONE barrier, ONE f64 fold.
// B: LDS dbuf 2 x 16KB via gld_lds; store octet (s&7)^(n&7), read octet
// (sub*4+g)^(ncol&7)  -> 2 lanes/granule = b128 conflict floor.
// A: global->reg, prefetch-1. b = flat&7 == XCD. JSPLIT=4 partials + f64.
template <bool DIRECT>
__global__ __launch_bounds__(256, 4)
void gemm_mfma(const float* __restrict__ ag, const unsigned short* __restrict__ xs,
               float* __restrict__ outg, float* __restrict__ wp) {
  __shared__ __align__(16) unsigned short sB[2][2 * 64 * CHUNK];   // 2 x 16KB

  const int tid  = threadIdx.x;
  const int ln   = tid & 63;
  const int wv   = tid >> 6;
  const int ln15 = ln & 15;          // A row / B col / D col (in 16-tile)
  const int g    = ln >> 4;          // k-octet / D row-group
  const int bkey = ln15 & 7;         // == ncol & 7 for every nt (nt*16 % 8 == 0)

  const int flat = blockIdx.x;
  const int b    = flat & 7;                      // batch == XCD
  const int rr   = flat >> 3;
  const int bx   = rr & 31;
  const int z    = DIRECT ? 0 : ((rr >> 5) & 3);
  const int i0   = bx * 64;
  const int jb   = z * JPB;
  const int nch  = (DIRECT ? NROW : JPB) / CHUNK;   // 32 or 8

  const float* aA =
      ag + ((size_t)b * NROW + i0 + wv * 16 + ln15) * NROW + jb + g * 8;
  const unsigned short* xB = xs + (size_t)b * NF * NROW;

  // stage B chunk: 4 gld_lds/thread (2 lvl x 2 rounds of 256 slots).
  // slot s in [0,512): row n = s>>3 (64 f-rows, 8 octets each),
  // octet pos p = s&7 holds global octet p ^ (n&7).
  auto stageB = [&](int buf, int j0) {
#pragma unroll
    for (int lvl = 0; lvl < 2; ++lvl)
#pragma unroll
      for (int h = 0; h < 2; ++h) {
        const int s = h * 256 + tid;
        const int n = s >> 3;
        const int q = (s & 7) ^ (n & 7);
        gld16u(xB + (size_t)lvl * TOT + (size_t)n * NROW + j0 + q * 8,
               &sB[buf][0] + (lvl * 512 + h * 256 + wv * 64) * 8);
      }
  };

  double macc[4][4];
#pragma unroll
  for (int i = 0; i < 4; ++i)
#pragma unroll
    for (int j = 0; j < 4; ++j) macc[i][j] = 0.0;

  // 4 terms, ascending magnitude: a1x1, a1x0, a0x1, a0x0
  constexpr int AI[4] = {1, 1, 0, 0};
  constexpr int BI[4] = {1, 0, 1, 0};

  stageB(0, jb);
  f32x4 A0 = *(const f32x4*)(aA);          // sub0: k = g*8
  f32x4 A1 = *(const f32x4*)(aA + 4);
  f32x4 A2 = *(const f32x4*)(aA + 32);     // sub1: k = 32 + g*8
  f32x4 A3 = *(const f32x4*)(aA + 36);

#pragma unroll 1
  for (int t = 0; t < nch; ++t) {
    __syncthreads();                  // stage(t) visible; buf^1 free
    if (t + 1 < nch) stageB((t + 1) & 1, jb + (t + 1) * CHUNK);
    const int tn = (t + 1 < nch) ? (t + 1) : t;
    const float* aNxt = aA + (size_t)tn * CHUNK;
    f32x4 N0 = *(const f32x4*)(aNxt);
    f32x4 N1 = *(const f32x4*)(aNxt + 4);
    f32x4 N2 = *(const f32x4*)(aNxt + 32);
    f32x4 N3 = *(const f32x4*)(aNxt + 36);

    const unsigned short* sBb = &sB[t & 1][0];
    f32x4 c[4];
#pragma unroll
    for (int nt = 0; nt < 4; ++nt) c[nt] = (f32x4){0.f, 0.f, 0.f, 0.f};

#pragma unroll
    for (int sub = 0; sub < 2; ++sub) {
      fragh Af[2];
      split8h(sub ? A2 : A0, sub ? A3 : A1, Af);

      const int bq = (sub * 4 + g) ^ bkey;   // read octet within 8
#pragma unroll
      for (int ng = 0; ng < 2; ++ng) {
        fragh Bv[2][2];
#pragma unroll
        for (int nn = 0; nn < 2; ++nn) {
          const int ncol = (ng * 2 + nn) * 16 + ln15;
#pragma unroll
          for (int lvl = 0; lvl < 2; ++lvl)
            Bv[nn][lvl].u =
                *(const u16x8*)(sBb + lvl * 4096 + ncol * 64 + bq * 8);
        }
#pragma unroll
        for (int term = 0; term < 4; ++term)
#pragma unroll
          for (int nn = 0; nn < 2; ++nn) {
            const int nt = ng * 2 + nn;
            c[nt] = __builtin_amdgcn_mfma_f32_16x16x32_f16(
                Af[AI[term]].h, Bv[nn][BI[term]].h, c[nt], 0, 0, 0);
          }
      }
    }
    A0 = N0; A1 = N1; A2 = N2; A3 = N3;

#pragma unroll
    for (int nt = 0; nt < 4; ++nt) {         // one fold per 64 k
      macc[nt][0] += (double)c[nt].x;
      macc[nt][1] += (double)c[nt].y;
      macc[nt][2] += (double)c[nt].z;
      macc[nt][3] += (double)c[nt].w;
    }
  }

  // epilogue: D row = g*4 + r (within 16-tile), col = nt*16 + ln15
  if (DIRECT) {
#pragma unroll
    for (int nt = 0; nt < 4; ++nt)
#pragma unroll
      for (int r = 0; r < 4; ++r)
        outg[((size_t)b * NROW + i0 + wv * 16 + g * 4 + r) * NF + nt * 16 + ln15] =
            (macc[nt][r] > THRESH) ? 1.0f : 0.0f;
  } else {
    float* wb = wp + (size_t)z * TOT;
#pragma unroll
    for (int nt = 0; nt < 4; ++nt)
#pragma unroll
      for (int r = 0; r < 4; ++r)
        wb[((size_t)b * NROW + i0 + wv * 16 + g * 4 + r) * NF + nt * 16 + ln15] =
            (float)macc[nt][r];
  }
}

// ---- pass 3: reduce JSPLIT partials in f64, threshold (scaled) ----
__global__ __launch_bounds__(256)
void combine_thresh(const float* __restrict__ wsv, float* __restrict__ outg) {
  const size_t e = ((size_t)blockIdx.x * 256 + threadIdx.x) * 4;
  f32x4 p0 = *(const f32x4*)(wsv + e);
  f32x4 p1 = *(const f32x4*)(wsv + e + TOT);
  f32x4 p2 = *(const f32x4*)(wsv + e + 2 * TOT);
  f32x4 p3 = *(const f32x4*)(wsv + e + 3 * TOT);
  f32x4 o;
  o.x = (((double)p0.x + p1.x + p2.x + p3.x) > THRESH) ? 1.0f : 0.0f;
  o.y = (((double)p0.y + p1.y + p2.y + p3.y) > THRESH) ? 1.0f : 0.0f;
  o.z = (((double)p0.z + p1.z + p2.z + p3.z) > THRESH) ? 1.0f : 0.0f;
  o.w = (((double)p0.w + p1.w + p2.w + p3.w) > THRESH) ? 1.0f : 0.0f;
  *(f32x4*)(outg + e) = o;
}

extern "C" void kernel_launch(void* const* d_in, const int* in_sizes, int n_in,
                              void* d_out, int out_size, void* d_ws, size_t ws_size,
                              hipStream_t stream) {
  const float* x = (const float*)d_in[0];
  const float* a = (const float*)d_in[1];
  float* out = (float*)d_out;
  unsigned short* xs = (unsigned short*)d_ws;                 // 2 levels = 4 MB
  float* wp = (float*)((char*)d_ws + 2 * TOT * sizeof(unsigned short));

  prep_x<<<dim3(NROW / 64, BATCH), dim3(256), 0, stream>>>(x, xs);

  const size_t need = 2 * TOT * sizeof(unsigned short)
                    + (size_t)JSPLIT * TOT * sizeof(float);   // 20 MB
  if (ws_size >= need) {
    gemm_mfma<false><<<dim3(JSPLIT * BATCH * (NROW / 64)), dim3(256), 0, stream>>>(
        a, xs, out, wp);
    combine_thresh<<<dim3((unsigned)(TOT / 1024)), dim3(256), 0, stream>>>(wp, out);
  } else {
    gemm_mfma<true><<<dim3(BATCH * (NROW / 64)), dim3(256), 0, stream>>>(
        a, xs, out, nullptr);
  }
}